// Round 1
// baseline (190.985 us; speedup 1.0000x reference)
//
#include <hip/hip_runtime.h>

// 10 steps of anisotropic 2D heat stencil, 48x48 grid, B=16384 batches.
// Ghost ring = reflect pad of the INITIAL state, frozen across steps
// (reference pads once before lax.scan and only updates the interior).

constexpr int NXY   = 48;           // grid side
constexpr int NP    = 50;           // padded side
constexpr int CELLS = NXY * NXY;    // 2304
constexpr int NT    = 10;           // time steps
constexpr int TPB   = 256;          // threads per block
constexpr int PER   = CELLS / TPB;  // 9 cells per thread

__global__ __launch_bounds__(TPB) void pde_heat_kernel(
    const float* __restrict__ u0,
    const float* __restrict__ aw,
    const float* __restrict__ bw,
    float* __restrict__ out)
{
    __shared__ float P[NP * NP];     // padded image, 10000 B
    __shared__ float alpha_s[NXY];   // row coefficient (depends on i)
    __shared__ float beta_s[NXY];    // col coefficient (depends on j)

    const int tid = threadIdx.x;
    const long long b = blockIdx.x;
    const float* __restrict__ u = u0 + b * CELLS;
    float*       __restrict__ o = out + b * CELLS;

    // ---- coefficient rows (computed once per block; 2*pi*y etc.) ----
    // alpha = 0.5*dt*(a0 + a1 sin(2pi y) + a2 sin(4pi y))/dx^2 ; 0.5*dt/dx^2 = 1.152
    // beta  =     dt*(b0 + b1 cos(2pi x) + b2 cos(4pi x))/dy^2 ;     dt/dy^2 = 2.304
    if (tid < NXY) {
        float y  = (float)tid * (1.0f / 47.0f);
        float s1 = sinf(6.28318530717958647692f * y);
        float s2 = sinf(12.5663706143591729539f * y);
        alpha_s[tid] = 1.152f * (aw[0] + aw[1] * s1 + aw[2] * s2);
    } else if (tid >= 64 && tid < 64 + NXY) {
        int j    = tid - 64;
        float x  = (float)j * (1.0f / 47.0f);
        float c1 = cosf(6.28318530717958647692f * x);
        float c2 = cosf(12.5663706143591729539f * x);
        beta_s[j] = 2.304f * (bw[0] + bw[1] * c1 + bw[2] * c2);
    }

    // ---- interior load (coalesced: lane-consecutive addresses) ----
    int   idx9[PER];
    float a9[PER], b9[PER];
    #pragma unroll
    for (int k = 0; k < PER; ++k) {
        int c = tid + k * TPB;
        int i = c / NXY;
        int j = c - i * NXY;
        idx9[k] = (i + 1) * NP + (j + 1);
        P[idx9[k]] = u[c];
    }
    __syncthreads();

    // coefficients to registers (after barrier so alpha_s/beta_s are ready)
    #pragma unroll
    for (int k = 0; k < PER; ++k) {
        int c = tid + k * TPB;
        int i = c / NXY;
        int j = c - i * NXY;
        a9[k] = alpha_s[i];
        b9[k] = beta_s[j];
    }

    // ---- frozen reflect ghost ring, derived from LDS interior ----
    // phase A: left/right columns of rows 1..48  (P[i][0]=P[i][2], etc.)
    if (tid < NXY) {
        int i = tid + 1;
        P[i * NP + 0]      = P[i * NP + 2];
        P[i * NP + NP - 1] = P[i * NP + NP - 3];
    }
    __syncthreads();
    // phase B: full top/bottom rows incl. corners (row2/row47 now have col ghosts)
    if (tid < NP) {
        P[tid]                 = P[2 * NP + tid];
        P[(NP - 1) * NP + tid] = P[(NP - 3) * NP + tid];
    }
    __syncthreads();

    // ---- time loop entirely in LDS ----
    for (int t = 0; t < NT; ++t) {
        float nv[PER];
        #pragma unroll
        for (int k = 0; k < PER; ++k) {
            int idx  = idx9[k];
            float ui = P[idx];
            float uxx = P[idx + NP] - 2.0f * ui + P[idx - NP];
            float uyy = P[idx + 1]  - 2.0f * ui + P[idx - 1];
            nv[k] = ui + a9[k] * uxx + b9[k] * uyy;
        }
        __syncthreads();
        #pragma unroll
        for (int k = 0; k < PER; ++k) P[idx9[k]] = nv[k];
        __syncthreads();
    }

    // ---- store (coalesced) ----
    #pragma unroll
    for (int k = 0; k < PER; ++k) {
        int c = tid + k * TPB;
        o[c] = P[idx9[k]];
    }
}

extern "C" void kernel_launch(void* const* d_in, const int* in_sizes, int n_in,
                              void* d_out, int out_size, void* d_ws, size_t ws_size,
                              hipStream_t stream) {
    const float* u0 = (const float*)d_in[0];
    const float* aw = (const float*)d_in[1];
    const float* bw = (const float*)d_in[2];
    float* out = (float*)d_out;

    const int B = in_sizes[0] / CELLS;   // 16384
    pde_heat_kernel<<<B, TPB, 0, stream>>>(u0, aw, bw, out);
}

// Round 2
// 99.730 us; speedup vs baseline: 1.9150x; 1.9150x over previous
//
#include <hip/hip_runtime.h>

// 10 steps of anisotropic 2D heat stencil, 48x48, B=16384.
// One 64-lane wave per image; each lane holds a 6x6 patch in REGISTERS.
// LDS holds the padded image only for halo exchange + frozen reflect ghosts.
// Ghost ring = reflect pad of the INITIAL state, frozen across steps
// (reference pads once before lax.scan, updates interior only).

constexpr int NXY    = 48;
constexpr int CELLS  = NXY * NXY;       // 2304
constexpr int NT     = 10;
constexpr int TPB    = 64;              // one wave per block/image
constexpr int PS     = 6;               // patch side per lane (8x8 lanes)
constexpr int STRIDE = 60;              // LDS row stride (floats): bank-friendly, 16B-aligned
constexpr int COL0   = 4;               // interior col offset (16B aligned)
constexpr int ROWS   = 50;              // padded rows 0..49; interior rows 1..48

__global__ __launch_bounds__(TPB) void pde_heat_kernel(
    const float* __restrict__ u0,
    const float* __restrict__ aw,
    const float* __restrict__ bw,
    float* __restrict__ out)
{
    __shared__ float P[ROWS * STRIDE];   // 12000 B
    __shared__ float alpha_s[NXY];
    __shared__ float beta_s[NXY];

    const int tid = threadIdx.x;
    const long long b = blockIdx.x;
    const float* __restrict__ u = u0 + b * CELLS;
    float*       __restrict__ o = out + b * CELLS;

    // ---- coefficients: alpha(i) scales u_xx (axis-0 diff), beta(j) scales u_yy ----
    // 0.5*dt/dx^2 = 1.152 ; dt/dy^2 = 2.304 ; grid coord = idx/47
    if (tid < NXY) {
        float y  = (float)tid * (1.0f / 47.0f);
        float s1 = sinf(6.28318530717958647692f * y);
        float s2 = sinf(12.5663706143591729539f * y);
        alpha_s[tid] = 1.152f * (aw[0] + aw[1] * s1 + aw[2] * s2);
        float c1 = cosf(6.28318530717958647692f * y);
        float c2 = cosf(12.5663706143591729539f * y);
        beta_s[tid] = 2.304f * (bw[0] + bw[1] * c1 + bw[2] * c2);
    }

    // ---- stage interior, coalesced float4 (48 % 4 == 0 -> never crosses a row) ----
    const float4* __restrict__ u4 = (const float4*)u;
    #pragma unroll
    for (int k = 0; k < 9; ++k) {
        int g  = tid + k * TPB;          // float4 index, 576 total
        int i  = g / 12;
        int j4 = (g - i * 12) * 4;
        *(float4*)&P[(i + 1) * STRIDE + COL0 + j4] = u4[g];
    }
    __syncthreads();

    // ---- frozen reflect ghost ring (from LDS interior) ----
    if (tid < NXY) {                      // left/right ghost cols, padded rows 1..48
        int i = tid + 1;
        P[i * STRIDE + COL0 - 1]  = P[i * STRIDE + COL0 + 1];   // ghost = interior j=1
        P[i * STRIDE + COL0 + 48] = P[i * STRIDE + COL0 + 46];  // ghost = interior j=46
    }
    __syncthreads();
    if (tid < 50) {                       // top/bottom ghost rows incl. corners
        int col = COL0 - 1 + tid;
        P[0 * STRIDE + col]  = P[2 * STRIDE + col];
        P[49 * STRIDE + col] = P[47 * STRIDE + col];
    }
    __syncthreads();

    // ---- per-lane 6x6 patch ----
    const int r = tid >> 3, c = tid & 7;
    const int r0 = r * PS, c0 = c * PS;                // interior origin
    const int base = (r0 + 1) * STRIDE + COL0 + c0;    // LDS addr of patch (0,0)

    float ca[PS], cb[PS];
    #pragma unroll
    for (int t = 0; t < PS; ++t) { ca[t] = alpha_s[r0 + t]; cb[t] = beta_s[c0 + t]; }

    float v[PS][PS];
    #pragma unroll
    for (int ii = 0; ii < PS; ++ii)
        #pragma unroll
        for (int jj = 0; jj < PS; ++jj)
            v[ii][jj] = P[base + ii * STRIDE + jj];

    // ---- time loop: registers + LDS ring exchange ----
    for (int t = 0; t < NT; ++t) {
        float ht[PS], hb[PS], hl[PS], hr[PS];
        #pragma unroll
        for (int jj = 0; jj < PS; ++jj) {
            ht[jj] = P[base - STRIDE + jj];            // row above (neighbor ring / ghost)
            hb[jj] = P[base + PS * STRIDE + jj];       // row below
        }
        #pragma unroll
        for (int ii = 0; ii < PS; ++ii) {
            hl[ii] = P[base + ii * STRIDE - 1];        // col left
            hr[ii] = P[base + ii * STRIDE + PS];       // col right
        }
        __syncthreads();                               // all u^t reads done before overwrite

        float up[PS];
        #pragma unroll
        for (int jj = 0; jj < PS; ++jj) up[jj] = ht[jj];
        #pragma unroll
        for (int ii = 0; ii < PS; ++ii) {
            float cur[PS];
            #pragma unroll
            for (int jj = 0; jj < PS; ++jj) cur[jj] = v[ii][jj];
            #pragma unroll
            for (int jj = 0; jj < PS; ++jj) {
                float below = (ii < PS - 1) ? v[ii + 1][jj] : hb[jj];
                float left  = (jj > 0)      ? cur[jj - 1]   : hl[ii];
                float right = (jj < PS - 1) ? cur[jj + 1]   : hr[ii];
                float uxx = (up[jj] + below) - 2.0f * cur[jj];
                float uyy = (left + right)   - 2.0f * cur[jj];
                v[ii][jj] = cur[jj] + ca[ii] * uxx + cb[jj] * uyy;
            }
            #pragma unroll
            for (int jj = 0; jj < PS; ++jj) up[jj] = cur[jj];
        }

        // write my u^{t+1} ring (20 cells)
        #pragma unroll
        for (int jj = 0; jj < PS; ++jj) {
            P[base + jj]                    = v[0][jj];
            P[base + (PS - 1) * STRIDE + jj] = v[PS - 1][jj];
        }
        #pragma unroll
        for (int ii = 1; ii < PS - 1; ++ii) {
            P[base + ii * STRIDE]          = v[ii][0];
            P[base + ii * STRIDE + PS - 1] = v[ii][PS - 1];
        }
        __syncthreads();                               // ring visible for next step
    }

    // ---- write back: regs -> LDS -> coalesced float4 global ----
    #pragma unroll
    for (int ii = 0; ii < PS; ++ii)
        #pragma unroll
        for (int jj = 0; jj < PS; ++jj)
            P[base + ii * STRIDE + jj] = v[ii][jj];
    __syncthreads();

    float4* __restrict__ o4 = (float4*)o;
    #pragma unroll
    for (int k = 0; k < 9; ++k) {
        int g  = tid + k * TPB;
        int i  = g / 12;
        int j4 = (g - i * 12) * 4;
        o4[g] = *(const float4*)&P[(i + 1) * STRIDE + COL0 + j4];
    }
}

extern "C" void kernel_launch(void* const* d_in, const int* in_sizes, int n_in,
                              void* d_out, int out_size, void* d_ws, size_t ws_size,
                              hipStream_t stream) {
    const float* u0 = (const float*)d_in[0];
    const float* aw = (const float*)d_in[1];
    const float* bw = (const float*)d_in[2];
    float* out = (float*)d_out;

    const int B = in_sizes[0] / CELLS;   // 16384
    pde_heat_kernel<<<B, TPB, 0, stream>>>(u0, aw, bw, out);
}